// Round 7
// baseline (355.252 us; speedup 1.0000x reference)
//
#include <hip/hip_runtime.h>
#include <hip/hip_bf16.h>
#include <math.h>

// Problem constants
#define NC 3
#define NK 64
#define KK 3
#define K2 9
#define PAD 1
#define SCALE 4
#define S2 16
#define MID 4
#define B 4
#define H 128
#define W 128
#define HW (H*W)          // 16384
#define CIN 67            // NK + NC
#define OUT_HW (H*SCALE)  // 512
#define CST 64            // xcat: 64 bf16 per pixel, stored PLANE-MAJOR:
                          // [8 planes][HW][8ch] (16 B/px/plane, coalesced)

typedef short bf16x8 __attribute__((ext_vector_type(8)));
typedef float f32x4 __attribute__((ext_vector_type(4)));
typedef float f32x2 __attribute__((ext_vector_type(2)));
typedef unsigned int u32x4 __attribute__((ext_vector_type(4)));
typedef unsigned int u32x2 __attribute__((ext_vector_type(2)));

__device__ __forceinline__ float fast_sigmoid(float v) { return 1.f / (1.f + __expf(-v)); }
__device__ __forceinline__ float fast_tanh(float v) { return 2.f / (1.f + __expf(-2.f * v)) - 1.f; }

// fp32 -> bf16 round-to-nearest-even (verified; v_cvt_pk_bf16_f32 regressed
// absmax in R2 — do not use)
__device__ __forceinline__ unsigned short f2bf(float f) {
    unsigned int u = __float_as_uint(f);
    unsigned int r = (u + 0x7FFFu + ((u >> 16) & 1u)) >> 16;
    return (unsigned short)r;
}

// unpack a u32 holding 2 bf16 into a float2 {lo, hi}
__device__ __forceinline__ f32x2 unpk(unsigned int u) {
    f32x2 r;
    r[0] = __uint_as_float(u << 16);
    r[1] = __uint_as_float(u & 0xffff0000u);
    return r;
}

// load a zero-padded 3x3 patch of one channel plane (HxW) at (y,x)
__device__ __forceinline__ void load_patch(const float* __restrict__ xc, int y, int x, float* p) {
#pragma unroll
    for (int dy = -1; dy <= 1; dy++) {
#pragma unroll
        for (int dx = -1; dx <= 1; dx++) {
            int yy = y + dy, xx = x + dx;
            float v = (yy >= 0 && yy < H && xx >= 0 && xx < W) ? xc[yy * W + xx] : 0.f;
            p[(dy + 1) * 3 + (dx + 1)] = v;
        }
    }
}

// ---------------------------------------------------------------------------
// Prepack LSTM weights into M=192 A-fragments (12 M-tiles), bf16.
// ---------------------------------------------------------------------------
__global__ void k_prepL(const float* __restrict__ lw, unsigned short* __restrict__ aplk) {
    int g = blockIdx.x;            // M-tile 0..11
    int tid = threadIdx.x;         // 0..511
    int lane = tid >> 3, j = tid & 7;
    int o = g * 16 + (lane & 15);
    int k = ((lane >> 4) << 3) + j;
    float val = 0.f;
    if (k < 27) {
        int c = k / 9, tap = k % 9;
        int gate = o >> 6, nk = o & 63;
        int base = (gate == 0) ? 0 : (gate == 1) ? 2 * NK : 3 * NK;
        val = lw[(size_t)(base + nk) * (CIN * 9) + c * 9 + tap];
    }
    aplk[(size_t)g * 512 + tid] = f2bf(val);
}

// ---------------------------------------------------------------------------
// ConvLSTM as MFMA implicit GEMM. Also writes lrp (fused k_lr). Plane-major
// xcat output.
// ---------------------------------------------------------------------------
__global__ __launch_bounds__(256, 4) void k_lstm(const float* __restrict__ X,
                                                 const unsigned short* __restrict__ aplk,
                                                 const float* __restrict__ lb,
                                                 unsigned short* __restrict__ xcatA,
                                                 float* __restrict__ hid_out,
                                                 float* __restrict__ cell_out,
                                                 float* __restrict__ lrp) {
    int tid = threadIdx.x;
    int lane = tid & 63;
    int nt = __builtin_amdgcn_readfirstlane(tid >> 6);
    int blk = blockIdx.x;
    int sg = (blk & 7) * 128 + (blk >> 3);
    int b = sg >> 8;
    int hwbase = (sg & 255) * 64;
    int n = lane & 15, q = lane >> 4;
    int hw = hwbase + nt * 16 + n;
    int y = hw >> 7, x = hw & (W - 1);

    if (nt == 0) {
        int px = hwbase + lane;
        f32x4 v = {X[(size_t)(b * NC + 0) * HW + px], X[(size_t)(b * NC + 1) * HW + px],
                   X[(size_t)(b * NC + 2) * HW + px], 0.f};
        *(f32x4*)(lrp + ((size_t)b * HW + px) * 4) = v;
    }

    bf16x8 bf;
#pragma unroll
    for (int j = 0; j < 8; j++) {
        int k = q * 8 + j;
        float v = 0.f;
        if (k < 27) {
            int c = k / 9, tap = k % 9;
            int ky = tap / 3, kx = tap % 3;
            int yy = y + ky - 1, xx = x + kx - 1;
            if (yy >= 0 && yy < H && xx >= 0 && xx < W)
                v = X[(size_t)(b * NC + c) * HW + yy * W + xx];
        }
        bf[j] = (short)f2bf(v);
    }

    f32x4 acc[12];
#pragma unroll
    for (int mt = 0; mt < 12; mt++) { f32x4 z = {0.f, 0.f, 0.f, 0.f}; acc[mt] = z; }
#pragma unroll
    for (int mt = 0; mt < 12; mt++) {
        bf16x8 af = *(const bf16x8*)(aplk + (size_t)mt * 512 + lane * 8);
        acc[mt] = __builtin_amdgcn_mfma_f32_16x16x32_bf16(af, bf, acc[mt], 0, 0, 0);
    }

    unsigned short* xo = xcatA + (size_t)b * HW * CST;   // batch base, plane-major
#pragma unroll
    for (int mt = 0; mt < 4; mt++) {
        float hv4[4];
#pragma unroll
        for (int r = 0; r < 4; r++) {
            int nk = mt * 16 + q * 4 + r;
            float gi = acc[mt][r] + lb[nk];
            float go = acc[mt + 4][r] + lb[2 * NK + nk];
            float gg = acc[mt + 8][r] + lb[3 * NK + nk];
            float cv = fast_sigmoid(gi) * fast_tanh(gg);
            float hv = fast_sigmoid(go) * fast_tanh(cv);
            hv4[r] = hv;
            hid_out[(size_t)(b * NK + nk) * HW + hw] = hv;
            cell_out[(size_t)(b * NK + nk) * HW + hw] = cv;
        }
        u32x2 st;
        st[0] = (unsigned int)f2bf(hv4[0]) | ((unsigned int)f2bf(hv4[1]) << 16);
        st[1] = (unsigned int)f2bf(hv4[2]) | ((unsigned int)f2bf(hv4[3]) << 16);
        int p = 2 * mt + (q >> 1);
        *(u32x2*)(xo + (((size_t)p * HW + hw) << 3) + (q & 1) * 4) = st;
    }
}

// ---------------------------------------------------------------------------
// Prepack deform weights dw[o<64][c<67][k<9] into MFMA A-fragment order, bf16.
// ---------------------------------------------------------------------------
__global__ void k_prepA(const float* __restrict__ w, unsigned short* __restrict__ apk) {
    int g = blockIdx.x;            // (tap*3+ks)*4+mt
    int tid = threadIdx.x;         // 0..511
    int lane = tid >> 3, j = tid & 7;
    int mt = g & 3, r = g >> 2;    // r = tap*3+ks
    int ks = r % 3, tap = r / 3;
    int o = mt * 16 + (lane & 15);
    int c = ks * 32 + ((lane >> 4) << 3) + j;
    float val = (c < CIN) ? w[(size_t)o * (CIN * 9) + c * 9 + tap] : 0.f;
    apk[(size_t)g * 512 + tid] = f2bf(val);
}

// Prepack offset(18)+mask(9) conv weights into M=32 A-fragments, bf16.
__global__ void k_prepOM(const float* __restrict__ ow, const float* __restrict__ mw,
                         unsigned short* __restrict__ apk) {
    int g = blockIdx.x;            // (tap*3+kss)*2+mt
    int tid = threadIdx.x;         // 0..511
    int lane = tid >> 3, j = tid & 7;
    int mt = g & 1, r = g >> 1;    // r = tap*3+kss
    int kss = r % 3, tap = r / 3;
    int o = mt * 16 + (lane & 15);
    int c = kss * 32 + ((lane >> 4) << 3) + j;
    float val = 0.f;
    if (c < CIN) {
        if (o < 18) val = ow[(size_t)o * (CIN * 9) + c * 9 + tap];
        else if (o < 27) val = mw[(size_t)(o - 18) * (CIN * 9) + c * 9 + tap];
    }
    apk[(size_t)g * 512 + tid] = f2bf(val);
}

// ---------------------------------------------------------------------------
// FUSED offset/mask conv + deformable conv — wave-independent, plane-major
// xcat (R6), now 2-deep software-pipelined via MACRO-GENERATED NAMED
// variables (no arrays/structs/lambdas -> SROA-proof; R4/R5 spilled).
// Each tap's plane-0 gathers are staged one tap ahead; plane-1 + lr gathers
// issue at step-top, covered by the ks0 blend+MFMAs. sched_barrier(0) after
// each LOAD pins issue order (compiler otherwise sinks loads to their use:
// R6 VGPR=56). Arithmetic identical to verified R3/R6.
// ---------------------------------------------------------------------------
#define SB __builtin_amdgcn_sched_barrier(0)

#define P1_CALC(T) \
    const int yy_##T = y + (T / 3) - 1, xx_##T = x + (T % 3) - 1; \
    const bool vld_##T = (yy_##T >= 0 && yy_##T < H && xx_##T >= 0 && xx_##T < W); \
    const int ii_##T = min(max(yy_##T, 0), H - 1) * W + min(max(xx_##T, 0), W - 1);

#define P1_LOAD(T) \
    bf16x8 g0_##T = *(const bf16x8*)(pl0 + ((size_t)ii_##T << 3)); \
    bf16x8 g1_##T = *(const bf16x8*)(pl1 + ((size_t)ii_##T << 3));

#define P1_STEP(T) { \
    const unsigned short* ab = apkom + (size_t)(T * 6) * 512 + lane * 8; \
    bf16x8 z8 = {0, 0, 0, 0, 0, 0, 0, 0}; \
    bf16x8 b0 = g0_##T; if (!vld_##T) b0 = z8; \
    bf16x8 b1 = g1_##T; if (!vld_##T) b1 = z8; \
    _Pragma("unroll") for (int mt = 0; mt < 2; mt++) { \
        bf16x8 af = *(const bf16x8*)(ab + (size_t)(0 + mt) * 512); \
        acc2[mt] = __builtin_amdgcn_mfma_f32_16x16x32_bf16(af, b0, acc2[mt], 0, 0, 0); } \
    _Pragma("unroll") for (int mt = 0; mt < 2; mt++) { \
        bf16x8 af = *(const bf16x8*)(ab + (size_t)(2 + mt) * 512); \
        acc2[mt] = __builtin_amdgcn_mfma_f32_16x16x32_bf16(af, b1, acc2[mt], 0, 0, 0); } \
    bf16x8 bf2_ = z8; \
    if (q == 0 && vld_##T) { \
        f32x4 L = *(const f32x4*)(lb_ + ((size_t)ii_##T << 2)); \
        _Pragma("unroll") for (int j = 0; j < 4; j++) bf2_[j] = (short)f2bf(L[j]); } \
    _Pragma("unroll") for (int mt = 0; mt < 2; mt++) { \
        bf16x8 af = *(const bf16x8*)(ab + (size_t)(4 + mt) * 512); \
        acc2[mt] = __builtin_amdgcn_mfma_f32_16x16x32_bf16(af, bf2_, acc2[mt], 0, 0, 0); } }

#define P2_CALC(T) \
    const float omy_##T = somp[wid][n][T * 4 + 0]; \
    const float omx_##T = somp[wid][n][T * 4 + 1]; \
    const float m_##T = somp[wid][n][T * 4 + 2]; \
    const float py_##T = (float)(y + (T / 3) - 1) + omy_##T; \
    const float pxx_##T = (float)(x + (T % 3) - 1) + omx_##T; \
    const float fy_##T = floorf(py_##T), fx_##T = floorf(pxx_##T); \
    const float wy_##T = py_##T - fy_##T, wx_##T = pxx_##T - fx_##T; \
    const int y0_##T = (int)fy_##T, x0_##T = (int)fx_##T; \
    const float vy0_##T = (y0_##T >= 0 && y0_##T <= H - 1) ? 1.f : 0.f; \
    const float vy1_##T = (y0_##T + 1 >= 0 && y0_##T + 1 <= H - 1) ? 1.f : 0.f; \
    const float vx0_##T = (x0_##T >= 0 && x0_##T <= W - 1) ? 1.f : 0.f; \
    const float vx1_##T = (x0_##T + 1 >= 0 && x0_##T + 1 <= W - 1) ? 1.f : 0.f; \
    const int yc0_##T = min(max(y0_##T, 0), H - 1), yc1_##T = min(max(y0_##T + 1, 0), H - 1); \
    const int xc0_##T = min(max(x0_##T, 0), W - 1), xc1_##T = min(max(x0_##T + 1, 0), W - 1); \
    const float a00_##T = (1.f - wy_##T) * (1.f - wx_##T) * m_##T * vy0_##T * vx0_##T; \
    const float a01_##T = (1.f - wy_##T) * wx_##T * m_##T * vy0_##T * vx1_##T; \
    const float a10_##T = wy_##T * (1.f - wx_##T) * m_##T * vy1_##T * vx0_##T; \
    const float a11_##T = wy_##T * wx_##T * m_##T * vy1_##T * vx1_##T; \
    const int j00_##T = yc0_##T * W + xc0_##T, j01_##T = yc0_##T * W + xc1_##T; \
    const int j10_##T = yc1_##T * W + xc0_##T, j11_##T = yc1_##T * W + xc1_##T;

#define P2_LOAD(T) \
    u32x4 dA_##T = *(const u32x4*)(pl0 + ((size_t)j00_##T << 3)); \
    u32x4 dB_##T = *(const u32x4*)(pl0 + ((size_t)j01_##T << 3)); \
    u32x4 dC_##T = *(const u32x4*)(pl0 + ((size_t)j10_##T << 3)); \
    u32x4 dD_##T = *(const u32x4*)(pl0 + ((size_t)j11_##T << 3));

#define P2_STEP(T) { \
    const unsigned short* ab = apk + (size_t)(T * 12) * 512 + lane * 8; \
    u32x4 eA = *(const u32x4*)(pl1 + ((size_t)j00_##T << 3)); \
    u32x4 eB = *(const u32x4*)(pl1 + ((size_t)j01_##T << 3)); \
    u32x4 eC = *(const u32x4*)(pl1 + ((size_t)j10_##T << 3)); \
    u32x4 eD = *(const u32x4*)(pl1 + ((size_t)j11_##T << 3)); \
    f32x4 L00, L01, L10, L11; \
    if (q == 0) { \
        L00 = *(const f32x4*)(lb_ + ((size_t)j00_##T << 2)); \
        L01 = *(const f32x4*)(lb_ + ((size_t)j01_##T << 2)); \
        L10 = *(const f32x4*)(lb_ + ((size_t)j10_##T << 2)); \
        L11 = *(const f32x4*)(lb_ + ((size_t)j11_##T << 2)); \
    } \
    { bf16x8 bfv; unsigned int* bfu = (unsigned int*)&bfv; \
      _Pragma("unroll") for (int e = 0; e < 4; e++) { \
          f32x2 v = unpk(dA_##T[e]) * a00_##T + unpk(dB_##T[e]) * a01_##T \
                  + unpk(dC_##T[e]) * a10_##T + unpk(dD_##T[e]) * a11_##T; \
          bfu[e] = (unsigned int)f2bf(v[0]) | ((unsigned int)f2bf(v[1]) << 16); } \
      _Pragma("unroll") for (int mt = 0; mt < 4; mt++) { \
          bf16x8 af = *(const bf16x8*)(ab + (size_t)(0 + mt) * 512); \
          acc[mt] = __builtin_amdgcn_mfma_f32_16x16x32_bf16(af, bfv, acc[mt], 0, 0, 0); } } \
    { bf16x8 bfv; unsigned int* bfu = (unsigned int*)&bfv; \
      _Pragma("unroll") for (int e = 0; e < 4; e++) { \
          f32x2 v = unpk(eA[e]) * a00_##T + unpk(eB[e]) * a01_##T \
                  + unpk(eC[e]) * a10_##T + unpk(eD[e]) * a11_##T; \
          bfu[e] = (unsigned int)f2bf(v[0]) | ((unsigned int)f2bf(v[1]) << 16); } \
      _Pragma("unroll") for (int mt = 0; mt < 4; mt++) { \
          bf16x8 af = *(const bf16x8*)(ab + (size_t)(4 + mt) * 512); \
          acc[mt] = __builtin_amdgcn_mfma_f32_16x16x32_bf16(af, bfv, acc[mt], 0, 0, 0); } } \
    bf16x8 bf2_ = {0, 0, 0, 0, 0, 0, 0, 0}; \
    if (q == 0) { \
        f32x4 Lv = L00 * a00_##T + L01 * a01_##T + L10 * a10_##T + L11 * a11_##T; \
        _Pragma("unroll") for (int j = 0; j < 4; j++) bf2_[j] = (short)f2bf(Lv[j]); } \
    _Pragma("unroll") for (int mt = 0; mt < 4; mt++) { \
        bf16x8 af = *(const bf16x8*)(ab + (size_t)(8 + mt) * 512); \
        acc[mt] = __builtin_amdgcn_mfma_f32_16x16x32_bf16(af, bf2_, acc[mt], 0, 0, 0); } }

__global__ __launch_bounds__(256, 4) void k_offdef(const unsigned short* __restrict__ xcat,
                                                   const float* __restrict__ lrp,
                                                   const unsigned short* __restrict__ apkom,
                                                   const float* __restrict__ ob,
                                                   const float* __restrict__ mb,
                                                   const unsigned short* __restrict__ apk,
                                                   const float* __restrict__ bias,
                                                   unsigned short* __restrict__ xout) {
    __shared__ float somp[4][16][37];   // 9472 B; stride 37: conflict-free reads
    int tid = threadIdx.x;
    int lane = tid & 63;
    int wid = __builtin_amdgcn_readfirstlane(tid >> 6);
    int blk = blockIdx.x;                    // 0..1023
    int sg = (blk & 7) * 128 + (blk >> 3);   // XCD-contiguous strip id
    int b = sg >> 8;
    int hwbase = (sg & 255) * 64;
    int n = lane & 15, q = lane >> 4;
    int hw = hwbase + wid * 16 + n;
    int y = hw >> 7, x = hw & (W - 1);

    const unsigned short* xb = xcat + (size_t)b * HW * CST;   // plane-major base
    const unsigned short* pl0 = xb + (((size_t)q * HW) << 3);        // plane q (ks0)
    const unsigned short* pl1 = xb + (((size_t)(4 + q) * HW) << 3);  // plane 4+q (ks1)
    const float* lb_ = lrp + (size_t)b * HW * 4;

    // ---------------- phase 1: offset+mask conv, 2-deep pipelined ---------
    f32x4 acc2[2];
#pragma unroll
    for (int mt = 0; mt < 2; mt++) { f32x4 z = {0.f, 0.f, 0.f, 0.f}; acc2[mt] = z; }
    {
        P1_CALC(0) P1_LOAD(0)
        P1_CALC(1) P1_LOAD(1) SB; P1_STEP(0)
        P1_CALC(2) P1_LOAD(2) SB; P1_STEP(1)
        P1_CALC(3) P1_LOAD(3) SB; P1_STEP(2)
        P1_CALC(4) P1_LOAD(4) SB; P1_STEP(3)
        P1_CALC(5) P1_LOAD(5) SB; P1_STEP(4)
        P1_CALC(6) P1_LOAD(6) SB; P1_STEP(5)
        P1_CALC(7) P1_LOAD(7) SB; P1_STEP(6)
        P1_CALC(8) P1_LOAD(8) SB; P1_STEP(7)
        P1_STEP(8)
    }
    // LDS transpose: lane (n,q) holds o = mt*16+q*4+r for pixel n
#pragma unroll
    for (int mt = 0; mt < 2; mt++)
#pragma unroll
        for (int r = 0; r < 4; r++) {
            int o = mt * 16 + q * 4 + r;
            float s = acc2[mt][r];
            if (o < 18)
                somp[wid][n][(o >> 1) * 4 + (o & 1)] = s + ob[o];
            else if (o < 27)
                somp[wid][n][(o - 18) * 4 + 2] = 2.f * fast_sigmoid(s + mb[o - 18]);
        }
    __syncthreads();

    // ---------------- phase 2: deformable conv, 2-deep pipelined ----------
    f32x4 acc[4];
#pragma unroll
    for (int mt = 0; mt < 4; mt++) { f32x4 z = {0.f, 0.f, 0.f, 0.f}; acc[mt] = z; }
    {
        P2_CALC(0) P2_LOAD(0)
        P2_CALC(1) P2_LOAD(1) SB; P2_STEP(0)
        P2_CALC(2) P2_LOAD(2) SB; P2_STEP(1)
        P2_CALC(3) P2_LOAD(3) SB; P2_STEP(2)
        P2_CALC(4) P2_LOAD(4) SB; P2_STEP(3)
        P2_CALC(5) P2_LOAD(5) SB; P2_STEP(4)
        P2_CALC(6) P2_LOAD(6) SB; P2_STEP(5)
        P2_CALC(7) P2_LOAD(7) SB; P2_STEP(6)
        P2_CALC(8) P2_LOAD(8) SB; P2_STEP(7)
        P2_STEP(8)
    }

    // direct epilogue: lane (n,q) stores o = mt*16+q*4+r (plane-major)
    unsigned short* xo = xout + (size_t)b * HW * CST;
#pragma unroll
    for (int mt = 0; mt < 4; mt++) {
        float s[4];
#pragma unroll
        for (int r = 0; r < 4; r++) {
            int o = mt * 16 + q * 4 + r;
            s[r] = acc[mt][r] + bias[o];
        }
        u32x2 st;
        st[0] = (unsigned int)f2bf(s[0]) | ((unsigned int)f2bf(s[1]) << 16);
        st[1] = (unsigned int)f2bf(s[2]) | ((unsigned int)f2bf(s[3]) << 16);
        int p = 2 * mt + (q >> 1);
        *(u32x2*)(xo + (((size_t)p * HW + hw) << 3) + (q & 1) * 4) = st;
    }
}

// ---------------------------------------------------------------------------
// Final 3-channel conv, tap-split across 4 waves with LDS reduction.
// Plane-major xcat reads: adjacent lanes (adjacent px) coalesce.
// ---------------------------------------------------------------------------
__global__ __launch_bounds__(256, 4) void k_conv3(const unsigned short* __restrict__ xcat,
                                                  const float* __restrict__ lrp,
                                                  const float* __restrict__ cw,
                                                  const float* __restrict__ cb,
                                                  float* __restrict__ y3) {
    __shared__ float red[4 * 3 * 64];  // 3072 B
    int tid = threadIdx.x;
    int lane = tid & 63;
    int wid = __builtin_amdgcn_readfirstlane(tid >> 6);
    int blk = blockIdx.x;
    int sg = (blk & 7) * 128 + (blk >> 3);
    int b = sg >> 8;
    int hwbase = (sg & 255) * 64;
    int hw = hwbase + lane;
    int y = hw >> 7, x = hw & (W - 1);
    int t0 = (wid == 0) ? 0 : 3 + (wid - 1) * 2;
    int t1 = (wid == 0) ? 3 : t0 + 2;

    float a0 = 0.f, a1 = 0.f, a2 = 0.f;
    const unsigned short* xb = xcat + (size_t)b * HW * CST;
    const float* lb_ = lrp + (size_t)b * HW * 4;
#pragma unroll 1
    for (int tap = t0; tap < t1; tap++) {
        int ky = tap / 3, kx = tap - ky * 3;
        int yy = y + ky - 1, xx = x + kx - 1;
        if (yy < 0 || yy >= H || xx < 0 || xx >= W) continue;
        int ii = yy * W + xx;
#pragma unroll
        for (int c8 = 0; c8 < 8; c8++) {
            u32x4 d = *(const u32x4*)(xb + (((size_t)c8 * HW + ii) << 3));
#pragma unroll
            for (int e = 0; e < 4; e++) {
                int c = c8 * 8 + e * 2;
                float lo = __uint_as_float(d[e] << 16);
                float hi = __uint_as_float(d[e] & 0xffff0000u);
                a0 += lo * cw[0 * (CIN * 9) + c * 9 + tap] + hi * cw[0 * (CIN * 9) + (c + 1) * 9 + tap];
                a1 += lo * cw[1 * (CIN * 9) + c * 9 + tap] + hi * cw[1 * (CIN * 9) + (c + 1) * 9 + tap];
                a2 += lo * cw[2 * (CIN * 9) + c * 9 + tap] + hi * cw[2 * (CIN * 9) + (c + 1) * 9 + tap];
            }
        }
        f32x4 L = *(const f32x4*)(lb_ + ((size_t)ii << 2));
#pragma unroll
        for (int e = 0; e < 3; e++) {
            a0 += L[e] * cw[0 * (CIN * 9) + (64 + e) * 9 + tap];
            a1 += L[e] * cw[1 * (CIN * 9) + (64 + e) * 9 + tap];
            a2 += L[e] * cw[2 * (CIN * 9) + (64 + e) * 9 + tap];
        }
    }
    red[(wid * 3 + 0) * 64 + lane] = a0;
    red[(wid * 3 + 1) * 64 + lane] = a1;
    red[(wid * 3 + 2) * 64 + lane] = a2;
    __syncthreads();
    if (tid < 192) {
        int oc = tid >> 6, px = tid & 63;
        float s = red[(0 * 3 + oc) * 64 + px] + red[(1 * 3 + oc) * 64 + px]
                + red[(2 * 3 + oc) * 64 + px] + red[(3 * 3 + oc) * 64 + px];
        y3[(size_t)(b * NC + oc) * HW + hwbase + px] = s + cb[oc];
    }
}

// global average pool: one block per (b,c)
__global__ __launch_bounds__(256) void k_pool(const float* __restrict__ y3,
                                              float* __restrict__ pooled) {
    int bc = blockIdx.x;  // 0..11
    const float* p = y3 + (size_t)bc * HW;
    float s = 0.f;
    for (int i = threadIdx.x; i < HW; i += 256) s += p[i];
    __shared__ float red[256];
    red[threadIdx.x] = s;
    __syncthreads();
    for (int off = 128; off > 0; off >>= 1) {
        if (threadIdx.x < off) red[threadIdx.x] += red[threadIdx.x + off];
        __syncthreads();
    }
    if (threadIdx.x == 0) pooled[bc] = red[0] / (float)HW;
}

// ---------------------------------------------------------------------------
// Fused DDF upsample. Per block sy = blockIdx.y is constant and sx = si, so
// the 4 si-results per channel form one contiguous float4 output row —
// accumulate into ov[3] and store 3 coalesced float4s (was 12 scalar
// stores at stride 16B, 25% efficiency).
// ---------------------------------------------------------------------------
__global__ __launch_bounds__(256) void k_ddf(const float* __restrict__ y3,
                                             const float* __restrict__ spw,
                                             const float* __restrict__ spb,
                                             const float* __restrict__ pooled,
                                             const float* __restrict__ ch_w1,
                                             const float* __restrict__ ch_b1,
                                             const float* __restrict__ ch_w2,
                                             const float* __restrict__ ch_b2,
                                             float* __restrict__ out) {
    __shared__ float s_spw[4 * K2 * NC * 9];  // 972
    __shared__ float s_spb[4 * K2];           // 36
    __shared__ float s_ch[4 * NC * K2];       // 108
    int t = blockIdx.x * blockDim.x + threadIdx.x;
    int b = t >> 14, hw = t & (HW - 1), y = hw >> 7, x = hw & (W - 1);
    int s0 = blockIdx.y * 4;
    for (int i = threadIdx.x; i < 4 * K2 * NC * 9; i += 256) s_spw[i] = spw[s0 * K2 * NC * 9 + i];
    if (threadIdx.x < 4 * K2) s_spb[threadIdx.x] = spb[s0 * K2 + threadIdx.x];
    if (threadIdx.x < 4 * NC * K2) {
        int t2 = threadIdx.x;
        int si = t2 / (NC * K2), kk = t2 - si * (NC * K2);
        int s = s0 + si;
        float a = ch_b2[s * (NC * K2) + kk];
#pragma unroll
        for (int m = 0; m < MID; m++) {
            float h1 = ch_b1[s * MID + m];
#pragma unroll
            for (int c = 0; c < NC; c++) h1 += pooled[b * NC + c] * ch_w1[(s * MID + m) * NC + c];
            a += fmaxf(h1, 0.f) * ch_w2[(s * (NC * K2) + kk) * MID + m];
        }
        s_ch[t2] = a;
    }
    __syncthreads();
    float p[NC][9];
#pragma unroll
    for (int c = 0; c < NC; c++) load_patch(y3 + (b * NC + c) * HW, y, x, p[c]);
    f32x4 ov[NC];
#pragma unroll
    for (int si = 0; si < 4; si++) {
        float spv[K2];
#pragma unroll
        for (int k = 0; k < K2; k++) {
            float a = s_spb[si * K2 + k];
            const float* w = s_spw + (si * K2 + k) * (NC * 9);
#pragma unroll
            for (int c = 0; c < NC; c++)
#pragma unroll
                for (int tt = 0; tt < 9; tt++) a += p[c][tt] * w[c * 9 + tt];
            spv[k] = a;
        }
#pragma unroll
        for (int c = 0; c < NC; c++) {
            float a = 0.f;
            const float* chp = s_ch + (si * NC + c) * K2;
#pragma unroll
            for (int k = 0; k < K2; k++) a += p[c][k] * (chp[k] + spv[k]);
            ov[c][si] = fminf(fmaxf(a, 0.f), 255.f);
        }
    }
    int sy = s0 >> 2;  // = blockIdx.y (sx = si)
#pragma unroll
    for (int c = 0; c < NC; c++)
        *(f32x4*)(out + ((size_t)(b * NC + c) * OUT_HW + (y * SCALE + sy)) * OUT_HW + x * SCALE) = ov[c];
}

extern "C" void kernel_launch(void* const* d_in, const int* in_sizes, int n_in,
                              void* d_out, int out_size, void* d_ws, size_t ws_size,
                              hipStream_t stream) {
    const float* X = (const float*)d_in[0];
    const float* lstm_w = (const float*)d_in[1];
    const float* lstm_b = (const float*)d_in[2];
    const float* ow[3] = {(const float*)d_in[3], (const float*)d_in[9], (const float*)d_in[15]};
    const float* ob[3] = {(const float*)d_in[4], (const float*)d_in[10], (const float*)d_in[16]};
    const float* mw[3] = {(const float*)d_in[5], (const float*)d_in[11], (const float*)d_in[17]};
    const float* mb[3] = {(const float*)d_in[6], (const float*)d_in[12], (const float*)d_in[18]};
    const float* dw[3] = {(const float*)d_in[7], (const float*)d_in[13], (const float*)d_in[19]};
    const float* db[3] = {(const float*)d_in[8], (const float*)d_in[14], (const float*)d_in[20]};
    const float* conv_w = (const float*)d_in[21];
    const float* conv_b = (const float*)d_in[22];
    const float* sp_w = (const float*)d_in[23];
    const float* sp_b = (const float*)d_in[24];
    const float* ch_w1 = (const float*)d_in[25];
    const float* ch_b1 = (const float*)d_in[26];
    const float* ch_w2 = (const float*)d_in[27];
    const float* ch_b2 = (const float*)d_in[28];

    float* out = (float*)d_out;
    const size_t OUT_IMG = (size_t)B * NC * OUT_HW * OUT_HW;  // 3145728
    const size_t HIDSZ = (size_t)B * NK * HW;                 // 4194304
    float* hid_out = out + OUT_IMG;
    float* cell_out = out + OUT_IMG + HIDSZ;

    float* ws = (float*)d_ws;
    const size_t XCATF = (size_t)B * HW * CST / 2;  // bf16 xcat, in float units
    unsigned short* xcatA = (unsigned short*)ws;  ws += XCATF;
    unsigned short* xcatB = (unsigned short*)ws;  ws += XCATF;
    float* lrp = ws;              ws += (size_t)B * HW * 4;
    unsigned short* apk[3];
    for (int i = 0; i < 3; i++) { apk[i] = (unsigned short*)ws; ws += 108 * 512 / 2; }
    unsigned short* apkOM[3];
    for (int i = 0; i < 3; i++) { apkOM[i] = (unsigned short*)ws; ws += 54 * 512 / 2; }
    unsigned short* aplk = (unsigned short*)ws;  ws += 12 * 512 / 2;
    float* y3 = ws;               ws += (size_t)B * NC * HW;
    float* pooled = ws;           ws += 16;

    dim3 blk(256);
    dim3 g4(B * HW / 256, 4);
    dim3 gd(B * HW / 64);         // 1024 strips (64 px per block, 16 per wave)

    k_prepL<<<dim3(12), dim3(512), 0, stream>>>(lstm_w, aplk);
    for (int i = 0; i < 3; i++) {
        k_prepA<<<dim3(108), dim3(512), 0, stream>>>(dw[i], apk[i]);
        k_prepOM<<<dim3(54), dim3(512), 0, stream>>>(ow[i], mw[i], apkOM[i]);
    }
    k_lstm<<<gd, blk, 0, stream>>>(X, aplk, lstm_b, xcatA, hid_out, cell_out, lrp);

    // layer 1: xcatA -> xcatB (offmask fused into deform, plane-major xcat)
    k_offdef<<<gd, blk, 0, stream>>>(xcatA, lrp, apkOM[0], ob[0], mb[0], apk[0], db[0], xcatB);
    // layer 2: xcatB -> xcatA
    k_offdef<<<gd, blk, 0, stream>>>(xcatB, lrp, apkOM[1], ob[1], mb[1], apk[1], db[1], xcatA);
    // layer 3: xcatA -> xcatB
    k_offdef<<<gd, blk, 0, stream>>>(xcatA, lrp, apkOM[2], ob[2], mb[2], apk[2], db[2], xcatB);

    k_conv3<<<gd, blk, 0, stream>>>(xcatB, lrp, conv_w, conv_b, y3);
    k_pool<<<dim3(B * NC), blk, 0, stream>>>(y3, pooled);
    k_ddf<<<g4, blk, 0, stream>>>(y3, sp_w, sp_b, pooled, ch_w1, ch_b1, ch_w2, ch_b2, out);
}

// Round 8
// 345.170 us; speedup vs baseline: 1.0292x; 1.0292x over previous
//
#include <hip/hip_runtime.h>
#include <hip/hip_bf16.h>
#include <math.h>

// Problem constants
#define NC 3
#define NK 64
#define KK 3
#define K2 9
#define PAD 1
#define SCALE 4
#define S2 16
#define MID 4
#define B 4
#define H 128
#define W 128
#define HW (H*W)          // 16384
#define CIN 67            // NK + NC
#define OUT_HW (H*SCALE)  // 512
#define CST 64            // xcat: 64 bf16 per pixel, stored PLANE-MAJOR:
                          // [8 planes][HW][8ch] (16 B/px/plane, coalesced)

typedef short bf16x8 __attribute__((ext_vector_type(8)));
typedef float f32x4 __attribute__((ext_vector_type(4)));
typedef float f32x2 __attribute__((ext_vector_type(2)));
typedef unsigned int u32x4 __attribute__((ext_vector_type(4)));
typedef unsigned int u32x2 __attribute__((ext_vector_type(2)));

__device__ __forceinline__ float fast_sigmoid(float v) { return 1.f / (1.f + __expf(-v)); }
__device__ __forceinline__ float fast_tanh(float v) { return 2.f / (1.f + __expf(-2.f * v)) - 1.f; }

// fp32 -> bf16 round-to-nearest-even (verified; v_cvt_pk_bf16_f32 regressed
// absmax in R2 — do not use)
__device__ __forceinline__ unsigned short f2bf(float f) {
    unsigned int u = __float_as_uint(f);
    unsigned int r = (u + 0x7FFFu + ((u >> 16) & 1u)) >> 16;
    return (unsigned short)r;
}

// unpack a u32 holding 2 bf16 into a float2 {lo, hi}
__device__ __forceinline__ f32x2 unpk(unsigned int u) {
    f32x2 r;
    r[0] = __uint_as_float(u << 16);
    r[1] = __uint_as_float(u & 0xffff0000u);
    return r;
}

// load a zero-padded 3x3 patch of one channel plane (HxW) at (y,x)
__device__ __forceinline__ void load_patch(const float* __restrict__ xc, int y, int x, float* p) {
#pragma unroll
    for (int dy = -1; dy <= 1; dy++) {
#pragma unroll
        for (int dx = -1; dx <= 1; dx++) {
            int yy = y + dy, xx = x + dx;
            float v = (yy >= 0 && yy < H && xx >= 0 && xx < W) ? xc[yy * W + xx] : 0.f;
            p[(dy + 1) * 3 + (dx + 1)] = v;
        }
    }
}

// ---------------------------------------------------------------------------
// MERGED prepack kernel: one launch replaces 7 (prepL + 3x prepA + 3x prepOM).
// Block ranges: [0,12) LSTM M-tiles; [12,336) deform A-frags (108/layer);
// [336,498) offset/mask A-frags (54/layer). Block 0 also zeroes pooled
// (k_conv3 accumulates into it via atomics each launch).
// ---------------------------------------------------------------------------
__global__ void k_prep(const float* __restrict__ lw,
                       const float* __restrict__ dw0, const float* __restrict__ dw1,
                       const float* __restrict__ dw2,
                       const float* __restrict__ ow0, const float* __restrict__ ow1,
                       const float* __restrict__ ow2,
                       const float* __restrict__ mw0, const float* __restrict__ mw1,
                       const float* __restrict__ mw2,
                       unsigned short* __restrict__ aplk,
                       unsigned short* __restrict__ apk0, unsigned short* __restrict__ apk1,
                       unsigned short* __restrict__ apk2,
                       unsigned short* __restrict__ apkOM0, unsigned short* __restrict__ apkOM1,
                       unsigned short* __restrict__ apkOM2,
                       float* __restrict__ pooled) {
    int g = blockIdx.x;
    int tid = threadIdx.x;         // 0..511
    int lane = tid >> 3, j = tid & 7;
    if (g == 0 && tid < 16) pooled[tid] = 0.f;

    if (g < 12) {
        // LSTM weights -> M=192 A-fragments
        int o = g * 16 + (lane & 15);
        int k = ((lane >> 4) << 3) + j;
        float val = 0.f;
        if (k < 27) {
            int c = k / 9, tap = k % 9;
            int gate = o >> 6, nk = o & 63;
            int base = (gate == 0) ? 0 : (gate == 1) ? 2 * NK : 3 * NK;
            val = lw[(size_t)(base + nk) * (CIN * 9) + c * 9 + tap];
        }
        aplk[(size_t)g * 512 + tid] = f2bf(val);
    } else if (g < 336) {
        // deform weights: layer i, local block gg
        int gi = g - 12;
        int i = gi / 108, gg = gi - i * 108;
        const float* w = (i == 0) ? dw0 : (i == 1) ? dw1 : dw2;
        unsigned short* apk = (i == 0) ? apk0 : (i == 1) ? apk1 : apk2;
        int mt = gg & 3, r = gg >> 2;    // r = tap*3+ks
        int ks = r % 3, tap = r / 3;
        int o = mt * 16 + (lane & 15);
        int c = ks * 32 + ((lane >> 4) << 3) + j;
        float val = (c < CIN) ? w[(size_t)o * (CIN * 9) + c * 9 + tap] : 0.f;
        apk[(size_t)gg * 512 + tid] = f2bf(val);
    } else {
        // offset(18)+mask(9) weights: layer i, local block gg
        int gi = g - 336;
        int i = gi / 54, gg = gi - i * 54;
        const float* ow = (i == 0) ? ow0 : (i == 1) ? ow1 : ow2;
        const float* mw = (i == 0) ? mw0 : (i == 1) ? mw1 : mw2;
        unsigned short* apk = (i == 0) ? apkOM0 : (i == 1) ? apkOM1 : apkOM2;
        int mt = gg & 1, r = gg >> 1;    // r = tap*3+kss
        int kss = r % 3, tap = r / 3;
        int o = mt * 16 + (lane & 15);
        int c = kss * 32 + ((lane >> 4) << 3) + j;
        float val = 0.f;
        if (c < CIN) {
            if (o < 18) val = ow[(size_t)o * (CIN * 9) + c * 9 + tap];
            else if (o < 27) val = mw[(size_t)(o - 18) * (CIN * 9) + c * 9 + tap];
        }
        apk[(size_t)gg * 512 + tid] = f2bf(val);
    }
}

// ---------------------------------------------------------------------------
// ConvLSTM as MFMA implicit GEMM. Also writes lrp (fused k_lr). Plane-major
// xcat output.
// ---------------------------------------------------------------------------
__global__ __launch_bounds__(256, 4) void k_lstm(const float* __restrict__ X,
                                                 const unsigned short* __restrict__ aplk,
                                                 const float* __restrict__ lb,
                                                 unsigned short* __restrict__ xcatA,
                                                 float* __restrict__ hid_out,
                                                 float* __restrict__ cell_out,
                                                 float* __restrict__ lrp) {
    int tid = threadIdx.x;
    int lane = tid & 63;
    int nt = __builtin_amdgcn_readfirstlane(tid >> 6);
    int blk = blockIdx.x;
    int sg = (blk & 7) * 128 + (blk >> 3);
    int b = sg >> 8;
    int hwbase = (sg & 255) * 64;
    int n = lane & 15, q = lane >> 4;
    int hw = hwbase + nt * 16 + n;
    int y = hw >> 7, x = hw & (W - 1);

    if (nt == 0) {
        int px = hwbase + lane;
        f32x4 v = {X[(size_t)(b * NC + 0) * HW + px], X[(size_t)(b * NC + 1) * HW + px],
                   X[(size_t)(b * NC + 2) * HW + px], 0.f};
        *(f32x4*)(lrp + ((size_t)b * HW + px) * 4) = v;
    }

    bf16x8 bf;
#pragma unroll
    for (int j = 0; j < 8; j++) {
        int k = q * 8 + j;
        float v = 0.f;
        if (k < 27) {
            int c = k / 9, tap = k % 9;
            int ky = tap / 3, kx = tap % 3;
            int yy = y + ky - 1, xx = x + kx - 1;
            if (yy >= 0 && yy < H && xx >= 0 && xx < W)
                v = X[(size_t)(b * NC + c) * HW + yy * W + xx];
        }
        bf[j] = (short)f2bf(v);
    }

    f32x4 acc[12];
#pragma unroll
    for (int mt = 0; mt < 12; mt++) { f32x4 z = {0.f, 0.f, 0.f, 0.f}; acc[mt] = z; }
#pragma unroll
    for (int mt = 0; mt < 12; mt++) {
        bf16x8 af = *(const bf16x8*)(aplk + (size_t)mt * 512 + lane * 8);
        acc[mt] = __builtin_amdgcn_mfma_f32_16x16x32_bf16(af, bf, acc[mt], 0, 0, 0);
    }

    unsigned short* xo = xcatA + (size_t)b * HW * CST;   // batch base, plane-major
#pragma unroll
    for (int mt = 0; mt < 4; mt++) {
        float hv4[4];
#pragma unroll
        for (int r = 0; r < 4; r++) {
            int nk = mt * 16 + q * 4 + r;
            float gi = acc[mt][r] + lb[nk];
            float go = acc[mt + 4][r] + lb[2 * NK + nk];
            float gg = acc[mt + 8][r] + lb[3 * NK + nk];
            float cv = fast_sigmoid(gi) * fast_tanh(gg);
            float hv = fast_sigmoid(go) * fast_tanh(cv);
            hv4[r] = hv;
            hid_out[(size_t)(b * NK + nk) * HW + hw] = hv;
            cell_out[(size_t)(b * NK + nk) * HW + hw] = cv;
        }
        u32x2 st;
        st[0] = (unsigned int)f2bf(hv4[0]) | ((unsigned int)f2bf(hv4[1]) << 16);
        st[1] = (unsigned int)f2bf(hv4[2]) | ((unsigned int)f2bf(hv4[3]) << 16);
        int p = 2 * mt + (q >> 1);
        *(u32x2*)(xo + (((size_t)p * HW + hw) << 3) + (q & 1) * 4) = st;
    }
}

// ---------------------------------------------------------------------------
// FUSED offset/mask conv + deformable conv — wave-independent, plane-major
// xcat. EXACT R6 version (48.2 µs, VGPR 56, no spill). Software-pipelining
// attempts R4/R5/R7 all spilled (allocator caps at 64 VGPR and spills) —
// do not re-attempt at source level.
// ---------------------------------------------------------------------------
__global__ __launch_bounds__(256, 4) void k_offdef(const unsigned short* __restrict__ xcat,
                                                   const float* __restrict__ lrp,
                                                   const unsigned short* __restrict__ apkom,
                                                   const float* __restrict__ ob,
                                                   const float* __restrict__ mb,
                                                   const unsigned short* __restrict__ apk,
                                                   const float* __restrict__ bias,
                                                   unsigned short* __restrict__ xout) {
    __shared__ float somp[4][16][37];   // 9472 B; stride 37: conflict-free reads
    int tid = threadIdx.x;
    int lane = tid & 63;
    int wid = __builtin_amdgcn_readfirstlane(tid >> 6);
    int blk = blockIdx.x;                    // 0..1023
    int sg = (blk & 7) * 128 + (blk >> 3);   // XCD-contiguous strip id
    int b = sg >> 8;
    int hwbase = (sg & 255) * 64;
    int n = lane & 15, q = lane >> 4;
    int hw = hwbase + wid * 16 + n;
    int y = hw >> 7, x = hw & (W - 1);

    const unsigned short* xb = xcat + (size_t)b * HW * CST;   // plane-major base
    const unsigned short* pl0 = xb + (((size_t)q * HW) << 3);        // plane q (ks0)
    const unsigned short* pl1 = xb + (((size_t)(4 + q) * HW) << 3);  // plane 4+q (ks1)
    const float* lb_ = lrp + (size_t)b * HW * 4;

    // ---------------- phase 1: offset+mask conv (all 9 taps, this wave) ---
    {
        f32x4 acc2[2];
#pragma unroll
        for (int mt = 0; mt < 2; mt++) { f32x4 z = {0.f, 0.f, 0.f, 0.f}; acc2[mt] = z; }
#pragma unroll
        for (int tap = 0; tap < K2; tap++) {
            int ky = tap / 3, kx = tap - ky * 3;
            int yy = y + ky - 1, xx = x + kx - 1;
            bool vld = (yy >= 0 && yy < H && xx >= 0 && xx < W);
            int ii = min(max(yy, 0), H - 1) * W + min(max(xx, 0), W - 1);
            const unsigned short* ab = apkom + (size_t)(tap * 6) * 512 + lane * 8;
            // kss = 0: plane q; kss = 1: plane 4+q (coalesced across n)
            {
                bf16x8 bfv = *(const bf16x8*)(pl0 + ((size_t)ii << 3));
                if (!vld) { bf16x8 z = {0, 0, 0, 0, 0, 0, 0, 0}; bfv = z; }
#pragma unroll
                for (int mt = 0; mt < 2; mt++) {
                    bf16x8 af = *(const bf16x8*)(ab + (size_t)(0 * 2 + mt) * 512);
                    acc2[mt] = __builtin_amdgcn_mfma_f32_16x16x32_bf16(af, bfv, acc2[mt], 0, 0, 0);
                }
            }
            {
                bf16x8 bfv = *(const bf16x8*)(pl1 + ((size_t)ii << 3));
                if (!vld) { bf16x8 z = {0, 0, 0, 0, 0, 0, 0, 0}; bfv = z; }
#pragma unroll
                for (int mt = 0; mt < 2; mt++) {
                    bf16x8 af = *(const bf16x8*)(ab + (size_t)(1 * 2 + mt) * 512);
                    acc2[mt] = __builtin_amdgcn_mfma_f32_16x16x32_bf16(af, bfv, acc2[mt], 0, 0, 0);
                }
            }
            // kss = 2: lr channels (c 64..66) carried by q==0 lanes only
            bf16x8 bf2 = {0, 0, 0, 0, 0, 0, 0, 0};
            if (q == 0 && vld) {
                f32x4 L = *(const f32x4*)(lb_ + ((size_t)ii << 2));
#pragma unroll
                for (int j = 0; j < 4; j++) bf2[j] = (short)f2bf(L[j]);
            }
#pragma unroll
            for (int mt = 0; mt < 2; mt++) {
                bf16x8 af = *(const bf16x8*)(ab + (size_t)(4 + mt) * 512);
                acc2[mt] = __builtin_amdgcn_mfma_f32_16x16x32_bf16(af, bf2, acc2[mt], 0, 0, 0);
            }
        }
        // LDS transpose: lane (n,q) holds o = mt*16+q*4+r for pixel n
#pragma unroll
        for (int mt = 0; mt < 2; mt++)
#pragma unroll
            for (int r = 0; r < 4; r++) {
                int o = mt * 16 + q * 4 + r;
                float s = acc2[mt][r];
                if (o < 18)
                    somp[wid][n][(o >> 1) * 4 + (o & 1)] = s + ob[o];
                else if (o < 27)
                    somp[wid][n][(o - 18) * 4 + 2] = 2.f * fast_sigmoid(s + mb[o - 18]);
            }
    }
    __syncthreads();

    // ---------------- phase 2: deformable conv (all 9 taps, this wave) ----
    f32x4 acc[4];
#pragma unroll
    for (int mt = 0; mt < 4; mt++) { f32x4 z = {0.f, 0.f, 0.f, 0.f}; acc[mt] = z; }

#pragma unroll
    for (int tap = 0; tap < K2; tap++) {
        float omy = somp[wid][n][tap * 4 + 0];
        float omx = somp[wid][n][tap * 4 + 1];
        float m = somp[wid][n][tap * 4 + 2];
        int ky = tap / 3, kx = tap - ky * 3;
        float py = (float)(y + ky - 1) + omy;
        float px_ = (float)(x + kx - 1) + omx;
        float fy = floorf(py), fx = floorf(px_);
        float wy = py - fy, wx = px_ - fx;
        int y0 = (int)fy, x0 = (int)fx;
        int y1 = y0 + 1, x1 = x0 + 1;
        float vy0 = (y0 >= 0 && y0 <= H - 1) ? 1.f : 0.f;
        float vy1 = (y1 >= 0 && y1 <= H - 1) ? 1.f : 0.f;
        float vx0 = (x0 >= 0 && x0 <= W - 1) ? 1.f : 0.f;
        float vx1 = (x1 >= 0 && x1 <= W - 1) ? 1.f : 0.f;
        int yc0 = min(max(y0, 0), H - 1), yc1 = min(max(y1, 0), H - 1);
        int xc0 = min(max(x0, 0), W - 1), xc1 = min(max(x1, 0), W - 1);
        float a00 = (1.f - wy) * (1.f - wx) * m * vy0 * vx0;
        float a01 = (1.f - wy) * wx * m * vy0 * vx1;
        float a10 = wy * (1.f - wx) * m * vy1 * vx0;
        float a11 = wy * wx * m * vy1 * vx1;
        int j00 = yc0 * W + xc0, j01 = yc0 * W + xc1;
        int j10 = yc1 * W + xc0, j11 = yc1 * W + xc1;

        const unsigned short* ab = apk + (size_t)(tap * 12) * 512 + lane * 8;
        // ks = 0: plane q — coalesced when j(n) runs are consecutive
        {
            u32x4 d00 = *(const u32x4*)(pl0 + ((size_t)j00 << 3));
            u32x4 d01 = *(const u32x4*)(pl0 + ((size_t)j01 << 3));
            u32x4 d10 = *(const u32x4*)(pl0 + ((size_t)j10 << 3));
            u32x4 d11 = *(const u32x4*)(pl0 + ((size_t)j11 << 3));
            bf16x8 bf;
            unsigned int* bfu = (unsigned int*)&bf;
#pragma unroll
            for (int e = 0; e < 4; e++) {
                f32x2 v = unpk(d00[e]) * a00 + unpk(d01[e]) * a01
                        + unpk(d10[e]) * a10 + unpk(d11[e]) * a11;
                bfu[e] = (unsigned int)f2bf(v[0]) | ((unsigned int)f2bf(v[1]) << 16);
            }
#pragma unroll
            for (int mt = 0; mt < 4; mt++) {
                bf16x8 af = *(const bf16x8*)(ab + (size_t)(0 * 4 + mt) * 512);
                acc[mt] = __builtin_amdgcn_mfma_f32_16x16x32_bf16(af, bf, acc[mt], 0, 0, 0);
            }
        }
        // ks = 1: plane 4+q
        {
            u32x4 d00 = *(const u32x4*)(pl1 + ((size_t)j00 << 3));
            u32x4 d01 = *(const u32x4*)(pl1 + ((size_t)j01 << 3));
            u32x4 d10 = *(const u32x4*)(pl1 + ((size_t)j10 << 3));
            u32x4 d11 = *(const u32x4*)(pl1 + ((size_t)j11 << 3));
            bf16x8 bf;
            unsigned int* bfu = (unsigned int*)&bf;
#pragma unroll
            for (int e = 0; e < 4; e++) {
                f32x2 v = unpk(d00[e]) * a00 + unpk(d01[e]) * a01
                        + unpk(d10[e]) * a10 + unpk(d11[e]) * a11;
                bfu[e] = (unsigned int)f2bf(v[0]) | ((unsigned int)f2bf(v[1]) << 16);
            }
#pragma unroll
            for (int mt = 0; mt < 4; mt++) {
                bf16x8 af = *(const bf16x8*)(ab + (size_t)(1 * 4 + mt) * 512);
                acc[mt] = __builtin_amdgcn_mfma_f32_16x16x32_bf16(af, bf, acc[mt], 0, 0, 0);
            }
        }
        // ks = 2: lr channels via q==0 lanes
        bf16x8 bf2 = {0, 0, 0, 0, 0, 0, 0, 0};
        if (q == 0) {
            f32x4 L00 = *(const f32x4*)(lb_ + ((size_t)j00 << 2));
            f32x4 L01 = *(const f32x4*)(lb_ + ((size_t)j01 << 2));
            f32x4 L10 = *(const f32x4*)(lb_ + ((size_t)j10 << 2));
            f32x4 L11 = *(const f32x4*)(lb_ + ((size_t)j11 << 2));
            f32x4 Lv = L00 * a00 + L01 * a01 + L10 * a10 + L11 * a11;
#pragma unroll
            for (int j = 0; j < 4; j++) bf2[j] = (short)f2bf(Lv[j]);
        }
#pragma unroll
        for (int mt = 0; mt < 4; mt++) {
            bf16x8 af = *(const bf16x8*)(ab + (size_t)(2 * 4 + mt) * 512);
            acc[mt] = __builtin_amdgcn_mfma_f32_16x16x32_bf16(af, bf2, acc[mt], 0, 0, 0);
        }
    }

    // direct epilogue: lane (n,q) stores o = mt*16+q*4+r (plane-major)
    unsigned short* xo = xout + (size_t)b * HW * CST;
#pragma unroll
    for (int mt = 0; mt < 4; mt++) {
        float s[4];
#pragma unroll
        for (int r = 0; r < 4; r++) {
            int o = mt * 16 + q * 4 + r;
            s[r] = acc[mt][r] + bias[o];
        }
        u32x2 st;
        st[0] = (unsigned int)f2bf(s[0]) | ((unsigned int)f2bf(s[1]) << 16);
        st[1] = (unsigned int)f2bf(s[2]) | ((unsigned int)f2bf(s[3]) << 16);
        int p = 2 * mt + (q >> 1);
        *(u32x2*)(xo + (((size_t)p * HW + hw) << 3) + (q & 1) * 4) = st;
    }
}

// ---------------------------------------------------------------------------
// Final 3-channel conv, tap-split across 4 waves with LDS reduction.
// Now also accumulates the global average pool (fused k_pool): each oc-group
// of the epilogue is exactly one wave -> shfl reduce + one atomicAdd.
// pooled is zeroed by k_prep at the head of every launch sequence.
// ---------------------------------------------------------------------------
__global__ __launch_bounds__(256, 4) void k_conv3(const unsigned short* __restrict__ xcat,
                                                  const float* __restrict__ lrp,
                                                  const float* __restrict__ cw,
                                                  const float* __restrict__ cb,
                                                  float* __restrict__ y3,
                                                  float* __restrict__ pooled) {
    __shared__ float red[4 * 3 * 64];  // 3072 B
    int tid = threadIdx.x;
    int lane = tid & 63;
    int wid = __builtin_amdgcn_readfirstlane(tid >> 6);
    int blk = blockIdx.x;
    int sg = (blk & 7) * 128 + (blk >> 3);
    int b = sg >> 8;
    int hwbase = (sg & 255) * 64;
    int hw = hwbase + lane;
    int y = hw >> 7, x = hw & (W - 1);
    int t0 = (wid == 0) ? 0 : 3 + (wid - 1) * 2;
    int t1 = (wid == 0) ? 3 : t0 + 2;

    float a0 = 0.f, a1 = 0.f, a2 = 0.f;
    const unsigned short* xb = xcat + (size_t)b * HW * CST;
    const float* lb_ = lrp + (size_t)b * HW * 4;
#pragma unroll 1
    for (int tap = t0; tap < t1; tap++) {
        int ky = tap / 3, kx = tap - ky * 3;
        int yy = y + ky - 1, xx = x + kx - 1;
        if (yy < 0 || yy >= H || xx < 0 || xx >= W) continue;
        int ii = yy * W + xx;
#pragma unroll
        for (int c8 = 0; c8 < 8; c8++) {
            u32x4 d = *(const u32x4*)(xb + (((size_t)c8 * HW + ii) << 3));
#pragma unroll
            for (int e = 0; e < 4; e++) {
                int c = c8 * 8 + e * 2;
                float lo = __uint_as_float(d[e] << 16);
                float hi = __uint_as_float(d[e] & 0xffff0000u);
                a0 += lo * cw[0 * (CIN * 9) + c * 9 + tap] + hi * cw[0 * (CIN * 9) + (c + 1) * 9 + tap];
                a1 += lo * cw[1 * (CIN * 9) + c * 9 + tap] + hi * cw[1 * (CIN * 9) + (c + 1) * 9 + tap];
                a2 += lo * cw[2 * (CIN * 9) + c * 9 + tap] + hi * cw[2 * (CIN * 9) + (c + 1) * 9 + tap];
            }
        }
        f32x4 L = *(const f32x4*)(lb_ + ((size_t)ii << 2));
#pragma unroll
        for (int e = 0; e < 3; e++) {
            a0 += L[e] * cw[0 * (CIN * 9) + (64 + e) * 9 + tap];
            a1 += L[e] * cw[1 * (CIN * 9) + (64 + e) * 9 + tap];
            a2 += L[e] * cw[2 * (CIN * 9) + (64 + e) * 9 + tap];
        }
    }
    red[(wid * 3 + 0) * 64 + lane] = a0;
    red[(wid * 3 + 1) * 64 + lane] = a1;
    red[(wid * 3 + 2) * 64 + lane] = a2;
    __syncthreads();
    if (tid < 192) {
        int oc = tid >> 6, px = tid & 63;
        float s = red[(0 * 3 + oc) * 64 + px] + red[(1 * 3 + oc) * 64 + px]
                + red[(2 * 3 + oc) * 64 + px] + red[(3 * 3 + oc) * 64 + px];
        float v = s + cb[oc];
        y3[(size_t)(b * NC + oc) * HW + hwbase + px] = v;
        // fused pool: oc-group == one full wave; reduce + one atomic
        float r = v;
#pragma unroll
        for (int off = 32; off > 0; off >>= 1) r += __shfl_xor(r, off);
        if ((tid & 63) == 0) atomicAdd(&pooled[b * NC + oc], r * (1.f / (float)HW));
    }
}

// ---------------------------------------------------------------------------
// Fused DDF upsample. Per block sy = blockIdx.y is constant and sx = si, so
// the 4 si-results per channel form one contiguous float4 output row —
// 3 coalesced float4 stores per thread. Per-branch channel MLP computed
// in-block (fused k_ch); pooled comes from k_conv3's fused reduction.
// ---------------------------------------------------------------------------
__global__ __launch_bounds__(256) void k_ddf(const float* __restrict__ y3,
                                             const float* __restrict__ spw,
                                             const float* __restrict__ spb,
                                             const float* __restrict__ pooled,
                                             const float* __restrict__ ch_w1,
                                             const float* __restrict__ ch_b1,
                                             const float* __restrict__ ch_w2,
                                             const float* __restrict__ ch_b2,
                                             float* __restrict__ out) {
    __shared__ float s_spw[4 * K2 * NC * 9];  // 972
    __shared__ float s_spb[4 * K2];           // 36
    __shared__ float s_ch[4 * NC * K2];       // 108
    int t = blockIdx.x * blockDim.x + threadIdx.x;
    int b = t >> 14, hw = t & (HW - 1), y = hw >> 7, x = hw & (W - 1);
    int s0 = blockIdx.y * 4;
    for (int i = threadIdx.x; i < 4 * K2 * NC * 9; i += 256) s_spw[i] = spw[s0 * K2 * NC * 9 + i];
    if (threadIdx.x < 4 * K2) s_spb[threadIdx.x] = spb[s0 * K2 + threadIdx.x];
    if (threadIdx.x < 4 * NC * K2) {
        int t2 = threadIdx.x;
        int si = t2 / (NC * K2), kk = t2 - si * (NC * K2);
        int s = s0 + si;
        float a = ch_b2[s * (NC * K2) + kk];
#pragma unroll
        for (int m = 0; m < MID; m++) {
            float h1 = ch_b1[s * MID + m];
#pragma unroll
            for (int c = 0; c < NC; c++) h1 += pooled[b * NC + c] * ch_w1[(s * MID + m) * NC + c];
            a += fmaxf(h1, 0.f) * ch_w2[(s * (NC * K2) + kk) * MID + m];
        }
        s_ch[t2] = a;
    }
    __syncthreads();
    float p[NC][9];
#pragma unroll
    for (int c = 0; c < NC; c++) load_patch(y3 + (b * NC + c) * HW, y, x, p[c]);
    f32x4 ov[NC];
#pragma unroll
    for (int si = 0; si < 4; si++) {
        float spv[K2];
#pragma unroll
        for (int k = 0; k < K2; k++) {
            float a = s_spb[si * K2 + k];
            const float* w = s_spw + (si * K2 + k) * (NC * 9);
#pragma unroll
            for (int c = 0; c < NC; c++)
#pragma unroll
                for (int tt = 0; tt < 9; tt++) a += p[c][tt] * w[c * 9 + tt];
            spv[k] = a;
        }
#pragma unroll
        for (int c = 0; c < NC; c++) {
            float a = 0.f;
            const float* chp = s_ch + (si * NC + c) * K2;
#pragma unroll
            for (int k = 0; k < K2; k++) a += p[c][k] * (chp[k] + spv[k]);
            ov[c][si] = fminf(fmaxf(a, 0.f), 255.f);
        }
    }
    int sy = s0 >> 2;  // = blockIdx.y (sx = si)
#pragma unroll
    for (int c = 0; c < NC; c++)
        *(f32x4*)(out + ((size_t)(b * NC + c) * OUT_HW + (y * SCALE + sy)) * OUT_HW + x * SCALE) = ov[c];
}

extern "C" void kernel_launch(void* const* d_in, const int* in_sizes, int n_in,
                              void* d_out, int out_size, void* d_ws, size_t ws_size,
                              hipStream_t stream) {
    const float* X = (const float*)d_in[0];
    const float* lstm_w = (const float*)d_in[1];
    const float* lstm_b = (const float*)d_in[2];
    const float* ow[3] = {(const float*)d_in[3], (const float*)d_in[9], (const float*)d_in[15]};
    const float* ob[3] = {(const float*)d_in[4], (const float*)d_in[10], (const float*)d_in[16]};
    const float* mw[3] = {(const float*)d_in[5], (const float*)d_in[11], (const float*)d_in[17]};
    const float* mb[3] = {(const float*)d_in[6], (const float*)d_in[12], (const float*)d_in[18]};
    const float* dw[3] = {(const float*)d_in[7], (const float*)d_in[13], (const float*)d_in[19]};
    const float* db[3] = {(const float*)d_in[8], (const float*)d_in[14], (const float*)d_in[20]};
    const float* conv_w = (const float*)d_in[21];
    const float* conv_b = (const float*)d_in[22];
    const float* sp_w = (const float*)d_in[23];
    const float* sp_b = (const float*)d_in[24];
    const float* ch_w1 = (const float*)d_in[25];
    const float* ch_b1 = (const float*)d_in[26];
    const float* ch_w2 = (const float*)d_in[27];
    const float* ch_b2 = (const float*)d_in[28];

    float* out = (float*)d_out;
    const size_t OUT_IMG = (size_t)B * NC * OUT_HW * OUT_HW;  // 3145728
    const size_t HIDSZ = (size_t)B * NK * HW;                 // 4194304
    float* hid_out = out + OUT_IMG;
    float* cell_out = out + OUT_IMG + HIDSZ;

    float* ws = (float*)d_ws;
    const size_t XCATF = (size_t)B * HW * CST / 2;  // bf16 xcat, in float units
    unsigned short* xcatA = (unsigned short*)ws;  ws += XCATF;
    unsigned short* xcatB = (unsigned short*)ws;  ws += XCATF;
    float* lrp = ws;              ws += (size_t)B * HW * 4;
    unsigned short* apk[3];
    for (int i = 0; i < 3; i++) { apk[i] = (unsigned short*)ws; ws += 108 * 512 / 2; }
    unsigned short* apkOM[3];
    for (int i = 0; i < 3; i++) { apkOM[i] = (unsigned short*)ws; ws += 54 * 512 / 2; }
    unsigned short* aplk = (unsigned short*)ws;  ws += 12 * 512 / 2;
    float* y3 = ws;               ws += (size_t)B * NC * HW;
    float* pooled = ws;           ws += 16;

    dim3 blk(256);
    dim3 g4(B * HW / 256, 4);
    dim3 gd(B * HW / 64);         // 1024 strips (64 px per block, 16 per wave)

    // one merged prep launch (was 7); also zeroes pooled for this iteration
    k_prep<<<dim3(498), dim3(512), 0, stream>>>(
        lstm_w, dw[0], dw[1], dw[2], ow[0], ow[1], ow[2], mw[0], mw[1], mw[2],
        aplk, apk[0], apk[1], apk[2], apkOM[0], apkOM[1], apkOM[2], pooled);

    k_lstm<<<gd, blk, 0, stream>>>(X, aplk, lstm_b, xcatA, hid_out, cell_out, lrp);

    // layer 1: xcatA -> xcatB (offmask fused into deform, plane-major xcat)
    k_offdef<<<gd, blk, 0, stream>>>(xcatA, lrp, apkOM[0], ob[0], mb[0], apk[0], db[0], xcatB);
    // layer 2: xcatB -> xcatA
    k_offdef<<<gd, blk, 0, stream>>>(xcatB, lrp, apkOM[1], ob[1], mb[1], apk[1], db[1], xcatA);
    // layer 3: xcatA -> xcatB
    k_offdef<<<gd, blk, 0, stream>>>(xcatA, lrp, apkOM[2], ob[2], mb[2], apk[2], db[2], xcatB);

    k_conv3<<<gd, blk, 0, stream>>>(xcatB, lrp, conv_w, conv_b, y3, pooled);
    k_ddf<<<g4, blk, 0, stream>>>(y3, sp_w, sp_b, pooled, ch_w1, ch_b1, ch_w2, ch_b2, out);
}

// Round 9
// 307.856 us; speedup vs baseline: 1.1540x; 1.1212x over previous
//
#include <hip/hip_runtime.h>
#include <hip/hip_bf16.h>
#include <math.h>

// Problem constants
#define NC 3
#define NK 64
#define KK 3
#define K2 9
#define PAD 1
#define SCALE 4
#define S2 16
#define MID 4
#define B 4
#define H 128
#define W 128
#define HW (H*W)          // 16384
#define CIN 67            // NK + NC
#define OUT_HW (H*SCALE)  // 512
#define CST 64            // xcat: 64 bf16 per pixel, stored PLANE-MAJOR:
                          // [8 planes][HW][8ch] (16 B/px/plane, coalesced)
#define NSTRIPE 64        // pool accumulation stripes (1 cache line each)

typedef short bf16x8 __attribute__((ext_vector_type(8)));
typedef float f32x4 __attribute__((ext_vector_type(4)));
typedef float f32x2 __attribute__((ext_vector_type(2)));
typedef unsigned int u32x4 __attribute__((ext_vector_type(4)));
typedef unsigned int u32x2 __attribute__((ext_vector_type(2)));

__device__ __forceinline__ float fast_sigmoid(float v) { return 1.f / (1.f + __expf(-v)); }
__device__ __forceinline__ float fast_tanh(float v) { return 2.f / (1.f + __expf(-2.f * v)) - 1.f; }

// fp32 -> bf16 round-to-nearest-even (verified; v_cvt_pk_bf16_f32 regressed
// absmax in R2 — do not use)
__device__ __forceinline__ unsigned short f2bf(float f) {
    unsigned int u = __float_as_uint(f);
    unsigned int r = (u + 0x7FFFu + ((u >> 16) & 1u)) >> 16;
    return (unsigned short)r;
}

// unpack a u32 holding 2 bf16 into a float2 {lo, hi}
__device__ __forceinline__ f32x2 unpk(unsigned int u) {
    f32x2 r;
    r[0] = __uint_as_float(u << 16);
    r[1] = __uint_as_float(u & 0xffff0000u);
    return r;
}

// load a zero-padded 3x3 patch of one channel plane (HxW) at (y,x)
__device__ __forceinline__ void load_patch(const float* __restrict__ xc, int y, int x, float* p) {
#pragma unroll
    for (int dy = -1; dy <= 1; dy++) {
#pragma unroll
        for (int dx = -1; dx <= 1; dx++) {
            int yy = y + dy, xx = x + dx;
            float v = (yy >= 0 && yy < H && xx >= 0 && xx < W) ? xc[yy * W + xx] : 0.f;
            p[(dy + 1) * 3 + (dx + 1)] = v;
        }
    }
}

// ---------------------------------------------------------------------------
// MERGED prepack kernel (one launch replaces 7). Block ranges: [0,12) LSTM
// M-tiles; [12,336) deform A-frags; [336,498) offset/mask A-frags. Block 0
// also zeroes the striped pool buffer (64 stripes x 16 floats).
// ---------------------------------------------------------------------------
__global__ void k_prep(const float* __restrict__ lw,
                       const float* __restrict__ dw0, const float* __restrict__ dw1,
                       const float* __restrict__ dw2,
                       const float* __restrict__ ow0, const float* __restrict__ ow1,
                       const float* __restrict__ ow2,
                       const float* __restrict__ mw0, const float* __restrict__ mw1,
                       const float* __restrict__ mw2,
                       unsigned short* __restrict__ aplk,
                       unsigned short* __restrict__ apk0, unsigned short* __restrict__ apk1,
                       unsigned short* __restrict__ apk2,
                       unsigned short* __restrict__ apkOM0, unsigned short* __restrict__ apkOM1,
                       unsigned short* __restrict__ apkOM2,
                       float* __restrict__ pooledS) {
    int g = blockIdx.x;
    int tid = threadIdx.x;         // 0..511
    int lane = tid >> 3, j = tid & 7;
    if (g == 0) { pooledS[tid] = 0.f; pooledS[tid + 512] = 0.f; }

    if (g < 12) {
        int o = g * 16 + (lane & 15);
        int k = ((lane >> 4) << 3) + j;
        float val = 0.f;
        if (k < 27) {
            int c = k / 9, tap = k % 9;
            int gate = o >> 6, nk = o & 63;
            int base = (gate == 0) ? 0 : (gate == 1) ? 2 * NK : 3 * NK;
            val = lw[(size_t)(base + nk) * (CIN * 9) + c * 9 + tap];
        }
        aplk[(size_t)g * 512 + tid] = f2bf(val);
    } else if (g < 336) {
        int gi = g - 12;
        int i = gi / 108, gg = gi - i * 108;
        const float* w = (i == 0) ? dw0 : (i == 1) ? dw1 : dw2;
        unsigned short* apk = (i == 0) ? apk0 : (i == 1) ? apk1 : apk2;
        int mt = gg & 3, r = gg >> 2;    // r = tap*3+ks
        int ks = r % 3, tap = r / 3;
        int o = mt * 16 + (lane & 15);
        int c = ks * 32 + ((lane >> 4) << 3) + j;
        float val = (c < CIN) ? w[(size_t)o * (CIN * 9) + c * 9 + tap] : 0.f;
        apk[(size_t)gg * 512 + tid] = f2bf(val);
    } else {
        int gi = g - 336;
        int i = gi / 54, gg = gi - i * 54;
        const float* ow = (i == 0) ? ow0 : (i == 1) ? ow1 : ow2;
        const float* mw = (i == 0) ? mw0 : (i == 1) ? mw1 : mw2;
        unsigned short* apk = (i == 0) ? apkOM0 : (i == 1) ? apkOM1 : apkOM2;
        int mt = gg & 1, r = gg >> 1;    // r = tap*3+kss
        int kss = r % 3, tap = r / 3;
        int o = mt * 16 + (lane & 15);
        int c = kss * 32 + ((lane >> 4) << 3) + j;
        float val = 0.f;
        if (c < CIN) {
            if (o < 18) val = ow[(size_t)o * (CIN * 9) + c * 9 + tap];
            else if (o < 27) val = mw[(size_t)(o - 18) * (CIN * 9) + c * 9 + tap];
        }
        apk[(size_t)gg * 512 + tid] = f2bf(val);
    }
}

// ---------------------------------------------------------------------------
// ConvLSTM as MFMA implicit GEMM. Also writes lrp (fused k_lr). Plane-major
// xcat output.
// ---------------------------------------------------------------------------
__global__ __launch_bounds__(256, 4) void k_lstm(const float* __restrict__ X,
                                                 const unsigned short* __restrict__ aplk,
                                                 const float* __restrict__ lb,
                                                 unsigned short* __restrict__ xcatA,
                                                 float* __restrict__ hid_out,
                                                 float* __restrict__ cell_out,
                                                 float* __restrict__ lrp) {
    int tid = threadIdx.x;
    int lane = tid & 63;
    int nt = __builtin_amdgcn_readfirstlane(tid >> 6);
    int blk = blockIdx.x;
    int sg = (blk & 7) * 128 + (blk >> 3);
    int b = sg >> 8;
    int hwbase = (sg & 255) * 64;
    int n = lane & 15, q = lane >> 4;
    int hw = hwbase + nt * 16 + n;
    int y = hw >> 7, x = hw & (W - 1);

    if (nt == 0) {
        int px = hwbase + lane;
        f32x4 v = {X[(size_t)(b * NC + 0) * HW + px], X[(size_t)(b * NC + 1) * HW + px],
                   X[(size_t)(b * NC + 2) * HW + px], 0.f};
        *(f32x4*)(lrp + ((size_t)b * HW + px) * 4) = v;
    }

    bf16x8 bf;
#pragma unroll
    for (int j = 0; j < 8; j++) {
        int k = q * 8 + j;
        float v = 0.f;
        if (k < 27) {
            int c = k / 9, tap = k % 9;
            int ky = tap / 3, kx = tap % 3;
            int yy = y + ky - 1, xx = x + kx - 1;
            if (yy >= 0 && yy < H && xx >= 0 && xx < W)
                v = X[(size_t)(b * NC + c) * HW + yy * W + xx];
        }
        bf[j] = (short)f2bf(v);
    }

    f32x4 acc[12];
#pragma unroll
    for (int mt = 0; mt < 12; mt++) { f32x4 z = {0.f, 0.f, 0.f, 0.f}; acc[mt] = z; }
#pragma unroll
    for (int mt = 0; mt < 12; mt++) {
        bf16x8 af = *(const bf16x8*)(aplk + (size_t)mt * 512 + lane * 8);
        acc[mt] = __builtin_amdgcn_mfma_f32_16x16x32_bf16(af, bf, acc[mt], 0, 0, 0);
    }

    unsigned short* xo = xcatA + (size_t)b * HW * CST;   // batch base, plane-major
#pragma unroll
    for (int mt = 0; mt < 4; mt++) {
        float hv4[4];
#pragma unroll
        for (int r = 0; r < 4; r++) {
            int nk = mt * 16 + q * 4 + r;
            float gi = acc[mt][r] + lb[nk];
            float go = acc[mt + 4][r] + lb[2 * NK + nk];
            float gg = acc[mt + 8][r] + lb[3 * NK + nk];
            float cv = fast_sigmoid(gi) * fast_tanh(gg);
            float hv = fast_sigmoid(go) * fast_tanh(cv);
            hv4[r] = hv;
            hid_out[(size_t)(b * NK + nk) * HW + hw] = hv;
            cell_out[(size_t)(b * NK + nk) * HW + hw] = cv;
        }
        u32x2 st;
        st[0] = (unsigned int)f2bf(hv4[0]) | ((unsigned int)f2bf(hv4[1]) << 16);
        st[1] = (unsigned int)f2bf(hv4[2]) | ((unsigned int)f2bf(hv4[3]) << 16);
        int p = 2 * mt + (q >> 1);
        *(u32x2*)(xo + (((size_t)p * HW + hw) << 3) + (q & 1) * 4) = st;
    }
}

// ---------------------------------------------------------------------------
// FUSED offset/mask conv + deformable conv — wave-independent, plane-major
// xcat. EXACT R6 version (48.2 µs, VGPR 56, no spill). Software-pipelining
// attempts R4/R5/R7 all spilled — do not re-attempt at source level.
// ---------------------------------------------------------------------------
__global__ __launch_bounds__(256, 4) void k_offdef(const unsigned short* __restrict__ xcat,
                                                   const float* __restrict__ lrp,
                                                   const unsigned short* __restrict__ apkom,
                                                   const float* __restrict__ ob,
                                                   const float* __restrict__ mb,
                                                   const unsigned short* __restrict__ apk,
                                                   const float* __restrict__ bias,
                                                   unsigned short* __restrict__ xout) {
    __shared__ float somp[4][16][37];   // 9472 B; stride 37: conflict-free reads
    int tid = threadIdx.x;
    int lane = tid & 63;
    int wid = __builtin_amdgcn_readfirstlane(tid >> 6);
    int blk = blockIdx.x;                    // 0..1023
    int sg = (blk & 7) * 128 + (blk >> 3);   // XCD-contiguous strip id
    int b = sg >> 8;
    int hwbase = (sg & 255) * 64;
    int n = lane & 15, q = lane >> 4;
    int hw = hwbase + wid * 16 + n;
    int y = hw >> 7, x = hw & (W - 1);

    const unsigned short* xb = xcat + (size_t)b * HW * CST;   // plane-major base
    const unsigned short* pl0 = xb + (((size_t)q * HW) << 3);        // plane q (ks0)
    const unsigned short* pl1 = xb + (((size_t)(4 + q) * HW) << 3);  // plane 4+q (ks1)
    const float* lb_ = lrp + (size_t)b * HW * 4;

    // ---------------- phase 1: offset+mask conv (all 9 taps, this wave) ---
    {
        f32x4 acc2[2];
#pragma unroll
        for (int mt = 0; mt < 2; mt++) { f32x4 z = {0.f, 0.f, 0.f, 0.f}; acc2[mt] = z; }
#pragma unroll
        for (int tap = 0; tap < K2; tap++) {
            int ky = tap / 3, kx = tap - ky * 3;
            int yy = y + ky - 1, xx = x + kx - 1;
            bool vld = (yy >= 0 && yy < H && xx >= 0 && xx < W);
            int ii = min(max(yy, 0), H - 1) * W + min(max(xx, 0), W - 1);
            const unsigned short* ab = apkom + (size_t)(tap * 6) * 512 + lane * 8;
            {
                bf16x8 bfv = *(const bf16x8*)(pl0 + ((size_t)ii << 3));
                if (!vld) { bf16x8 z = {0, 0, 0, 0, 0, 0, 0, 0}; bfv = z; }
#pragma unroll
                for (int mt = 0; mt < 2; mt++) {
                    bf16x8 af = *(const bf16x8*)(ab + (size_t)(0 * 2 + mt) * 512);
                    acc2[mt] = __builtin_amdgcn_mfma_f32_16x16x32_bf16(af, bfv, acc2[mt], 0, 0, 0);
                }
            }
            {
                bf16x8 bfv = *(const bf16x8*)(pl1 + ((size_t)ii << 3));
                if (!vld) { bf16x8 z = {0, 0, 0, 0, 0, 0, 0, 0}; bfv = z; }
#pragma unroll
                for (int mt = 0; mt < 2; mt++) {
                    bf16x8 af = *(const bf16x8*)(ab + (size_t)(1 * 2 + mt) * 512);
                    acc2[mt] = __builtin_amdgcn_mfma_f32_16x16x32_bf16(af, bfv, acc2[mt], 0, 0, 0);
                }
            }
            bf16x8 bf2 = {0, 0, 0, 0, 0, 0, 0, 0};
            if (q == 0 && vld) {
                f32x4 L = *(const f32x4*)(lb_ + ((size_t)ii << 2));
#pragma unroll
                for (int j = 0; j < 4; j++) bf2[j] = (short)f2bf(L[j]);
            }
#pragma unroll
            for (int mt = 0; mt < 2; mt++) {
                bf16x8 af = *(const bf16x8*)(ab + (size_t)(4 + mt) * 512);
                acc2[mt] = __builtin_amdgcn_mfma_f32_16x16x32_bf16(af, bf2, acc2[mt], 0, 0, 0);
            }
        }
#pragma unroll
        for (int mt = 0; mt < 2; mt++)
#pragma unroll
            for (int r = 0; r < 4; r++) {
                int o = mt * 16 + q * 4 + r;
                float s = acc2[mt][r];
                if (o < 18)
                    somp[wid][n][(o >> 1) * 4 + (o & 1)] = s + ob[o];
                else if (o < 27)
                    somp[wid][n][(o - 18) * 4 + 2] = 2.f * fast_sigmoid(s + mb[o - 18]);
            }
    }
    __syncthreads();

    // ---------------- phase 2: deformable conv (all 9 taps, this wave) ----
    f32x4 acc[4];
#pragma unroll
    for (int mt = 0; mt < 4; mt++) { f32x4 z = {0.f, 0.f, 0.f, 0.f}; acc[mt] = z; }

#pragma unroll
    for (int tap = 0; tap < K2; tap++) {
        float omy = somp[wid][n][tap * 4 + 0];
        float omx = somp[wid][n][tap * 4 + 1];
        float m = somp[wid][n][tap * 4 + 2];
        int ky = tap / 3, kx = tap - ky * 3;
        float py = (float)(y + ky - 1) + omy;
        float px_ = (float)(x + kx - 1) + omx;
        float fy = floorf(py), fx = floorf(px_);
        float wy = py - fy, wx = px_ - fx;
        int y0 = (int)fy, x0 = (int)fx;
        int y1 = y0 + 1, x1 = x0 + 1;
        float vy0 = (y0 >= 0 && y0 <= H - 1) ? 1.f : 0.f;
        float vy1 = (y1 >= 0 && y1 <= H - 1) ? 1.f : 0.f;
        float vx0 = (x0 >= 0 && x0 <= W - 1) ? 1.f : 0.f;
        float vx1 = (x1 >= 0 && x1 <= W - 1) ? 1.f : 0.f;
        int yc0 = min(max(y0, 0), H - 1), yc1 = min(max(y1, 0), H - 1);
        int xc0 = min(max(x0, 0), W - 1), xc1 = min(max(x1, 0), W - 1);
        float a00 = (1.f - wy) * (1.f - wx) * m * vy0 * vx0;
        float a01 = (1.f - wy) * wx * m * vy0 * vx1;
        float a10 = wy * (1.f - wx) * m * vy1 * vx0;
        float a11 = wy * wx * m * vy1 * vx1;
        int j00 = yc0 * W + xc0, j01 = yc0 * W + xc1;
        int j10 = yc1 * W + xc0, j11 = yc1 * W + xc1;

        const unsigned short* ab = apk + (size_t)(tap * 12) * 512 + lane * 8;
        {
            u32x4 d00 = *(const u32x4*)(pl0 + ((size_t)j00 << 3));
            u32x4 d01 = *(const u32x4*)(pl0 + ((size_t)j01 << 3));
            u32x4 d10 = *(const u32x4*)(pl0 + ((size_t)j10 << 3));
            u32x4 d11 = *(const u32x4*)(pl0 + ((size_t)j11 << 3));
            bf16x8 bf;
            unsigned int* bfu = (unsigned int*)&bf;
#pragma unroll
            for (int e = 0; e < 4; e++) {
                f32x2 v = unpk(d00[e]) * a00 + unpk(d01[e]) * a01
                        + unpk(d10[e]) * a10 + unpk(d11[e]) * a11;
                bfu[e] = (unsigned int)f2bf(v[0]) | ((unsigned int)f2bf(v[1]) << 16);
            }
#pragma unroll
            for (int mt = 0; mt < 4; mt++) {
                bf16x8 af = *(const bf16x8*)(ab + (size_t)(0 * 4 + mt) * 512);
                acc[mt] = __builtin_amdgcn_mfma_f32_16x16x32_bf16(af, bf, acc[mt], 0, 0, 0);
            }
        }
        {
            u32x4 d00 = *(const u32x4*)(pl1 + ((size_t)j00 << 3));
            u32x4 d01 = *(const u32x4*)(pl1 + ((size_t)j01 << 3));
            u32x4 d10 = *(const u32x4*)(pl1 + ((size_t)j10 << 3));
            u32x4 d11 = *(const u32x4*)(pl1 + ((size_t)j11 << 3));
            bf16x8 bf;
            unsigned int* bfu = (unsigned int*)&bf;
#pragma unroll
            for (int e = 0; e < 4; e++) {
                f32x2 v = unpk(d00[e]) * a00 + unpk(d01[e]) * a01
                        + unpk(d10[e]) * a10 + unpk(d11[e]) * a11;
                bfu[e] = (unsigned int)f2bf(v[0]) | ((unsigned int)f2bf(v[1]) << 16);
            }
#pragma unroll
            for (int mt = 0; mt < 4; mt++) {
                bf16x8 af = *(const bf16x8*)(ab + (size_t)(1 * 4 + mt) * 512);
                acc[mt] = __builtin_amdgcn_mfma_f32_16x16x32_bf16(af, bf, acc[mt], 0, 0, 0);
            }
        }
        bf16x8 bf2 = {0, 0, 0, 0, 0, 0, 0, 0};
        if (q == 0) {
            f32x4 L00 = *(const f32x4*)(lb_ + ((size_t)j00 << 2));
            f32x4 L01 = *(const f32x4*)(lb_ + ((size_t)j01 << 2));
            f32x4 L10 = *(const f32x4*)(lb_ + ((size_t)j10 << 2));
            f32x4 L11 = *(const f32x4*)(lb_ + ((size_t)j11 << 2));
            f32x4 Lv = L00 * a00 + L01 * a01 + L10 * a10 + L11 * a11;
#pragma unroll
            for (int j = 0; j < 4; j++) bf2[j] = (short)f2bf(Lv[j]);
        }
#pragma unroll
        for (int mt = 0; mt < 4; mt++) {
            bf16x8 af = *(const bf16x8*)(ab + (size_t)(2 * 4 + mt) * 512);
            acc[mt] = __builtin_amdgcn_mfma_f32_16x16x32_bf16(af, bf2, acc[mt], 0, 0, 0);
        }
    }

    // direct epilogue: lane (n,q) stores o = mt*16+q*4+r (plane-major)
    unsigned short* xo = xout + (size_t)b * HW * CST;
#pragma unroll
    for (int mt = 0; mt < 4; mt++) {
        float s[4];
#pragma unroll
        for (int r = 0; r < 4; r++) {
            int o = mt * 16 + q * 4 + r;
            s[r] = acc[mt][r] + bias[o];
        }
        u32x2 st;
        st[0] = (unsigned int)f2bf(s[0]) | ((unsigned int)f2bf(s[1]) << 16);
        st[1] = (unsigned int)f2bf(s[2]) | ((unsigned int)f2bf(s[3]) << 16);
        int p = 2 * mt + (q >> 1);
        *(u32x2*)(xo + (((size_t)p * HW + hw) << 3) + (q & 1) * 4) = st;
    }
}

// ---------------------------------------------------------------------------
// Final 3-channel conv, tap-split across 4 waves with LDS reduction.
// R9 fixes: (1) cw (1809 floats) staged in LDS — the runtime-tap scalar
// global loads were ~200 serialized s_loads/tap (R8: VALUBusy 7.8%, 54 µs);
// (2) pool atomicAdd striped over 64 cache lines (was 3072 RMWs on ONE line).
// ---------------------------------------------------------------------------
__global__ __launch_bounds__(256, 4) void k_conv3(const unsigned short* __restrict__ xcat,
                                                  const float* __restrict__ lrp,
                                                  const float* __restrict__ cw,
                                                  const float* __restrict__ cb,
                                                  float* __restrict__ y3,
                                                  float* __restrict__ pooledS) {
    __shared__ float red[4 * 3 * 64];      // 3072 B
    __shared__ float s_cw[NC * CIN * 9];   // 7236 B
    int tid = threadIdx.x;
    int lane = tid & 63;
    int wid = __builtin_amdgcn_readfirstlane(tid >> 6);
    int blk = blockIdx.x;
    int sg = (blk & 7) * 128 + (blk >> 3);
    int b = sg >> 8;
    int hwbase = (sg & 255) * 64;
    int hw = hwbase + lane;
    int y = hw >> 7, x = hw & (W - 1);
    int t0 = (wid == 0) ? 0 : 3 + (wid - 1) * 2;
    int t1 = (wid == 0) ? 3 : t0 + 2;

    for (int i = tid; i < NC * CIN * 9; i += 256) s_cw[i] = cw[i];
    __syncthreads();

    float a0 = 0.f, a1 = 0.f, a2 = 0.f;
    const unsigned short* xb = xcat + (size_t)b * HW * CST;
    const float* lb_ = lrp + (size_t)b * HW * 4;
#pragma unroll 1
    for (int tap = t0; tap < t1; tap++) {
        int ky = tap / 3, kx = tap - ky * 3;
        int yy = y + ky - 1, xx = x + kx - 1;
        if (yy < 0 || yy >= H || xx < 0 || xx >= W) continue;
        int ii = yy * W + xx;
#pragma unroll
        for (int c8 = 0; c8 < 8; c8++) {
            u32x4 d = *(const u32x4*)(xb + (((size_t)c8 * HW + ii) << 3));
#pragma unroll
            for (int e = 0; e < 4; e++) {
                int c = c8 * 8 + e * 2;
                float lo = __uint_as_float(d[e] << 16);
                float hi = __uint_as_float(d[e] & 0xffff0000u);
                a0 += lo * s_cw[0 * (CIN * 9) + c * 9 + tap] + hi * s_cw[0 * (CIN * 9) + (c + 1) * 9 + tap];
                a1 += lo * s_cw[1 * (CIN * 9) + c * 9 + tap] + hi * s_cw[1 * (CIN * 9) + (c + 1) * 9 + tap];
                a2 += lo * s_cw[2 * (CIN * 9) + c * 9 + tap] + hi * s_cw[2 * (CIN * 9) + (c + 1) * 9 + tap];
            }
        }
        f32x4 L = *(const f32x4*)(lb_ + ((size_t)ii << 2));
#pragma unroll
        for (int e = 0; e < 3; e++) {
            a0 += L[e] * s_cw[0 * (CIN * 9) + (64 + e) * 9 + tap];
            a1 += L[e] * s_cw[1 * (CIN * 9) + (64 + e) * 9 + tap];
            a2 += L[e] * s_cw[2 * (CIN * 9) + (64 + e) * 9 + tap];
        }
    }
    red[(wid * 3 + 0) * 64 + lane] = a0;
    red[(wid * 3 + 1) * 64 + lane] = a1;
    red[(wid * 3 + 2) * 64 + lane] = a2;
    __syncthreads();
    if (tid < 192) {
        int oc = tid >> 6, px = tid & 63;
        float s = red[(0 * 3 + oc) * 64 + px] + red[(1 * 3 + oc) * 64 + px]
                + red[(2 * 3 + oc) * 64 + px] + red[(3 * 3 + oc) * 64 + px];
        float v = s + cb[oc];
        y3[(size_t)(b * NC + oc) * HW + hwbase + px] = v;
        // fused pool: wave reduce + one atomic per wave, striped over 64
        // cache lines (stripe = blk&63; note b is a function of blk&7, so
        // each stripe only ever holds one batch's partials).
        float r = v;
#pragma unroll
        for (int off = 32; off > 0; off >>= 1) r += __shfl_xor(r, off);
        if ((tid & 63) == 0)
            atomicAdd(&pooledS[(blk & (NSTRIPE - 1)) * 16 + b * NC + oc], r * (1.f / (float)HW));
    }
}

// ---------------------------------------------------------------------------
// Fused DDF upsample. Coalesced f32x4 stores; per-branch channel MLP
// in-block; pool read = sum of the 64 stripes (3 threads, L2-hit loads).
// ---------------------------------------------------------------------------
__global__ __launch_bounds__(256) void k_ddf(const float* __restrict__ y3,
                                             const float* __restrict__ spw,
                                             const float* __restrict__ spb,
                                             const float* __restrict__ pooledS,
                                             const float* __restrict__ ch_w1,
                                             const float* __restrict__ ch_b1,
                                             const float* __restrict__ ch_w2,
                                             const float* __restrict__ ch_b2,
                                             float* __restrict__ out) {
    __shared__ float s_spw[4 * K2 * NC * 9];  // 972
    __shared__ float s_spb[4 * K2];           // 36
    __shared__ float s_ch[4 * NC * K2];       // 108
    __shared__ float s_pool[NC];
    int t = blockIdx.x * blockDim.x + threadIdx.x;
    int b = t >> 14, hw = t & (HW - 1), y = hw >> 7, x = hw & (W - 1);
    int s0 = blockIdx.y * 4;
    for (int i = threadIdx.x; i < 4 * K2 * NC * 9; i += 256) s_spw[i] = spw[s0 * K2 * NC * 9 + i];
    if (threadIdx.x < 4 * K2) s_spb[threadIdx.x] = spb[s0 * K2 + threadIdx.x];
    if (threadIdx.x < NC) {
        float s = 0.f;
#pragma unroll
        for (int st = 0; st < NSTRIPE; st++) s += pooledS[st * 16 + b * NC + threadIdx.x];
        s_pool[threadIdx.x] = s;
    }
    __syncthreads();
    if (threadIdx.x < 4 * NC * K2) {
        int t2 = threadIdx.x;
        int si = t2 / (NC * K2), kk = t2 - si * (NC * K2);
        int s = s0 + si;
        float a = ch_b2[s * (NC * K2) + kk];
#pragma unroll
        for (int m = 0; m < MID; m++) {
            float h1 = ch_b1[s * MID + m];
#pragma unroll
            for (int c = 0; c < NC; c++) h1 += s_pool[c] * ch_w1[(s * MID + m) * NC + c];
            a += fmaxf(h1, 0.f) * ch_w2[(s * (NC * K2) + kk) * MID + m];
        }
        s_ch[t2] = a;
    }
    __syncthreads();
    float p[NC][9];
#pragma unroll
    for (int c = 0; c < NC; c++) load_patch(y3 + (b * NC + c) * HW, y, x, p[c]);
    f32x4 ov[NC];
#pragma unroll
    for (int si = 0; si < 4; si++) {
        float spv[K2];
#pragma unroll
        for (int k = 0; k < K2; k++) {
            float a = s_spb[si * K2 + k];
            const float* w = s_spw + (si * K2 + k) * (NC * 9);
#pragma unroll
            for (int c = 0; c < NC; c++)
#pragma unroll
                for (int tt = 0; tt < 9; tt++) a += p[c][tt] * w[c * 9 + tt];
            spv[k] = a;
        }
#pragma unroll
        for (int c = 0; c < NC; c++) {
            float a = 0.f;
            const float* chp = s_ch + (si * NC + c) * K2;
#pragma unroll
            for (int k = 0; k < K2; k++) a += p[c][k] * (chp[k] + spv[k]);
            ov[c][si] = fminf(fmaxf(a, 0.f), 255.f);
        }
    }
    int sy = s0 >> 2;  // = blockIdx.y (sx = si)
#pragma unroll
    for (int c = 0; c < NC; c++)
        *(f32x4*)(out + ((size_t)(b * NC + c) * OUT_HW + (y * SCALE + sy)) * OUT_HW + x * SCALE) = ov[c];
}

extern "C" void kernel_launch(void* const* d_in, const int* in_sizes, int n_in,
                              void* d_out, int out_size, void* d_ws, size_t ws_size,
                              hipStream_t stream) {
    const float* X = (const float*)d_in[0];
    const float* lstm_w = (const float*)d_in[1];
    const float* lstm_b = (const float*)d_in[2];
    const float* ow[3] = {(const float*)d_in[3], (const float*)d_in[9], (const float*)d_in[15]};
    const float* ob[3] = {(const float*)d_in[4], (const float*)d_in[10], (const float*)d_in[16]};
    const float* mw[3] = {(const float*)d_in[5], (const float*)d_in[11], (const float*)d_in[17]};
    const float* mb[3] = {(const float*)d_in[6], (const float*)d_in[12], (const float*)d_in[18]};
    const float* dw[3] = {(const float*)d_in[7], (const float*)d_in[13], (const float*)d_in[19]};
    const float* db[3] = {(const float*)d_in[8], (const float*)d_in[14], (const float*)d_in[20]};
    const float* conv_w = (const float*)d_in[21];
    const float* conv_b = (const float*)d_in[22];
    const float* sp_w = (const float*)d_in[23];
    const float* sp_b = (const float*)d_in[24];
    const float* ch_w1 = (const float*)d_in[25];
    const float* ch_b1 = (const float*)d_in[26];
    const float* ch_w2 = (const float*)d_in[27];
    const float* ch_b2 = (const float*)d_in[28];

    float* out = (float*)d_out;
    const size_t OUT_IMG = (size_t)B * NC * OUT_HW * OUT_HW;  // 3145728
    const size_t HIDSZ = (size_t)B * NK * HW;                 // 4194304
    float* hid_out = out + OUT_IMG;
    float* cell_out = out + OUT_IMG + HIDSZ;

    float* ws = (float*)d_ws;
    const size_t XCATF = (size_t)B * HW * CST / 2;  // bf16 xcat, in float units
    unsigned short* xcatA = (unsigned short*)ws;  ws += XCATF;
    unsigned short* xcatB = (unsigned short*)ws;  ws += XCATF;
    float* lrp = ws;              ws += (size_t)B * HW * 4;
    unsigned short* apk[3];
    for (int i = 0; i < 3; i++) { apk[i] = (unsigned short*)ws; ws += 108 * 512 / 2; }
    unsigned short* apkOM[3];
    for (int i = 0; i < 3; i++) { apkOM[i] = (unsigned short*)ws; ws += 54 * 512 / 2; }
    unsigned short* aplk = (unsigned short*)ws;  ws += 12 * 512 / 2;
    float* y3 = ws;               ws += (size_t)B * NC * HW;
    float* pooledS = ws;          ws += NSTRIPE * 16;   // 64 stripes x 1 cache line

    dim3 blk(256);
    dim3 g4(B * HW / 256, 4);
    dim3 gd(B * HW / 64);         // 1024 strips (64 px per block, 16 per wave)

    // one merged prep launch; also zeroes pooledS for this iteration
    k_prep<<<dim3(498), dim3(512), 0, stream>>>(
        lstm_w, dw[0], dw[1], dw[2], ow[0], ow[1], ow[2], mw[0], mw[1], mw[2],
        aplk, apk[0], apk[1], apk[2], apkOM[0], apkOM[1], apkOM[2], pooledS);

    k_lstm<<<gd, blk, 0, stream>>>(X, aplk, lstm_b, xcatA, hid_out, cell_out, lrp);

    // layer 1: xcatA -> xcatB (offmask fused into deform, plane-major xcat)
    k_offdef<<<gd, blk, 0, stream>>>(xcatA, lrp, apkOM[0], ob[0], mb[0], apk[0], db[0], xcatB);
    // layer 2: xcatB -> xcatA
    k_offdef<<<gd, blk, 0, stream>>>(xcatB, lrp, apkOM[1], ob[1], mb[1], apk[1], db[1], xcatA);
    // layer 3: xcatA -> xcatB
    k_offdef<<<gd, blk, 0, stream>>>(xcatA, lrp, apkOM[2], ob[2], mb[2], apk[2], db[2], xcatB);

    k_conv3<<<gd, blk, 0, stream>>>(xcatB, lrp, conv_w, conv_b, y3, pooledS);
    k_ddf<<<g4, blk, 0, stream>>>(y3, sp_w, sp_b, pooledS, ch_w1, ch_b1, ch_w2, ch_b2, out);
}